// Round 4
// baseline (370.585 us; speedup 1.0000x reference)
//
#include <hip/hip_runtime.h>

// Problem constants (from reference)
constexpr int B   = 4;
constexpr int CF  = 3;    // feat channels
constexpr int CM  = 21;   // mask channels
constexpr int H   = 128;
constexpr int W   = 128;
constexpr int KS  = 7;
constexpr int PAD = 3;
constexpr int CENTER = (KS * KS) / 2;  // 24
constexpr int NNB = KS * KS - 1;       // 48 neighbors
constexpr int NUM_ITER = 10;

constexpr int TILE  = 16;
constexpr int TH    = TILE + 2 * PAD;  // 22
constexpr int TS    = 24;              // LDS row stride: ty*24 % 32 in {0,24,16,8} -> exact 2-way aliasing (free)
constexpr int HW    = H * W;

// ---------------------------------------------------------------------------
// Kernel 1: per-pixel 48-way softmax affinity from feats.
// aff layout: aff[((b*48 + n)*H + h)*W + w]  (n-major planes, coalesced in w)
// ---------------------------------------------------------------------------
__global__ __launch_bounds__(256) void aff_kernel(const float* __restrict__ feats,
                                                  float* __restrict__ aff) {
    __shared__ float tile[CF][TH][TS];
    const int tx = threadIdx.x, ty = threadIdx.y;
    const int bx = blockIdx.x * TILE, by = blockIdx.y * TILE;
    const int b  = blockIdx.z;
    const int tid = ty * TILE + tx;

    for (int c = 0; c < CF; ++c) {
        const float* src = feats + (size_t)(b * CF + c) * HW;
        for (int idx = tid; idx < TH * TH; idx += 256) {
            const int r  = idx / TH, cc = idx - r * TH;
            const int gh = min(max(by + r  - PAD, 0), H - 1);
            const int gw = min(max(bx + cc - PAD, 0), W - 1);
            tile[c][r][cc] = src[gh * W + gw];
        }
    }
    __syncthreads();

    // One-pass mean/sumsq variance over the 48 neighbors (ddof=1)
    float q[CF], inv[CF];
    #pragma unroll
    for (int c = 0; c < CF; ++c) {
        const float* tp = &tile[c][ty][tx];
        q[c] = tp[PAD * TS + PAD];
        float s = 0.f, s2 = 0.f;
        #pragma unroll
        for (int i = 0; i < KS; ++i)
            #pragma unroll
            for (int j = 0; j < KS; ++j) {
                if (i == PAD && j == PAD) continue;
                const float v = tp[i * TS + j];
                s += v; s2 += v * v;
            }
        const float mean = s * (1.0f / NNB);
        const float var  = fmaxf(s2 - (float)NNB * mean * mean, 0.f) * (1.0f / (NNB - 1));
        inv[c] = 1.0f / (1e-8f + 0.1f * sqrtf(var));
    }

    float a[NNB];
    float mx = -1e30f;
    #pragma unroll
    for (int i = 0; i < KS; ++i)
        #pragma unroll
        for (int j = 0; j < KS; ++j) {
            const int nn = i * KS + j;
            if (nn == CENTER) continue;
            const int n = (nn < CENTER) ? nn : nn - 1;
            float t = 0.f;
            #pragma unroll
            for (int c = 0; c < CF; ++c)
                t += fabsf(tile[c][ty + i][tx + j] - q[c]) * inv[c];
            a[n] = -t * (1.0f / CF);
            mx = fmaxf(mx, a[n]);
        }
    float ssum = 0.f;
    #pragma unroll
    for (int n = 0; n < NNB; ++n) { a[n] = __expf(a[n] - mx); ssum += a[n]; }
    const float rs = 1.0f / ssum;

    const int h = by + ty, w = bx + tx;
    #pragma unroll
    for (int n = 0; n < NNB; ++n)
        aff[(((size_t)b * NNB + n) * H + h) * W + w] = a[n] * rs;
}

// ---------------------------------------------------------------------------
// Kernel 2: one propagation iteration, ALL 21 channels per block.
// One staging burst + ONE __syncthreads per launch; aff in 48 registers.
// ---------------------------------------------------------------------------
__global__ __launch_bounds__(256) void iter_kernel(const float* __restrict__ mi,
                                                   const float* __restrict__ aff,
                                                   float* __restrict__ mo) {
    __shared__ float tile[CM][TH][TS];   // 44.4 KB
    const int tx = threadIdx.x, ty = threadIdx.y;
    const int bx = blockIdx.x * TILE, by = blockIdx.y * TILE;
    const int b  = blockIdx.z;
    const int h  = by + ty, w = bx + tx;

    // aff weights -> 48 registers (independent coalesced plane loads, L2-hit)
    float a[NNB];
    #pragma unroll
    for (int n = 0; n < NNB; ++n)
        a[n] = aff[(((size_t)b * NNB + n) * H + h) * W + w];

    // Stage all 21 channel halo tiles: 4 predicated slots/thread/channel
    bool vld[4]; int goff[4], loff[4];
    #pragma unroll
    for (int k = 0; k < 4; ++k) {
        const int r = ty + (k >> 1) * TILE, q = tx + (k & 1) * TILE;
        vld[k] = (r < TH) && (q < TH);
        const int gh = min(max(by + r - PAD, 0), H - 1);
        const int gw = min(max(bx + q - PAD, 0), W - 1);
        goff[k] = gh * W + gw;
        loff[k] = r * TS + q;
    }
    const float* src = mi + (size_t)b * CM * HW;
    float* tf = &tile[0][0][0];
    for (int c = 0; c < CM; ++c) {
        #pragma unroll
        for (int k = 0; k < 4; ++k)
            if (vld[k]) tf[c * (TH * TS) + loff[k]] = src[c * HW + goff[k]];
    }
    __syncthreads();

    // 21 channels x 48 taps, no further barriers
    float* dst = mo + (size_t)b * CM * HW + h * W + w;
    for (int c = 0; c < CM; ++c) {
        const float* tp = &tile[c][ty][tx];
        float s = 0.f;
        #pragma unroll
        for (int i = 0; i < KS; ++i)
            #pragma unroll
            for (int j = 0; j < KS; ++j) {
                const int nn = i * KS + j;
                if (nn == CENTER) continue;
                const int n = (nn < CENTER) ? nn : nn - 1;
                s += a[n] * tp[i * TS + j];
            }
        dst[c * HW] = s;
    }
}

// ---------------------------------------------------------------------------
extern "C" void kernel_launch(void* const* d_in, const int* in_sizes, int n_in,
                              void* d_out, int out_size, void* d_ws, size_t ws_size,
                              hipStream_t stream) {
    const float* feats = (const float*)d_in[0];
    const float* mask  = (const float*)d_in[1];
    float* out = (float*)d_out;

    float* aff  = (float*)d_ws;                               // 4*48*128*128*4 = 12.58 MB
    float* buf0 = aff  + (size_t)B * NNB * HW;                // 5.5 MB
    float* buf1 = buf0 + (size_t)B * CM  * HW;                // 5.5 MB

    dim3 blk(TILE, TILE);
    dim3 grid(W / TILE, H / TILE, B);
    aff_kernel<<<grid, blk, 0, stream>>>(feats, aff);

    const float* srcp = mask;
    for (int t = 1; t <= NUM_ITER; ++t) {
        float* dst = (t == NUM_ITER) ? out : ((t & 1) ? buf0 : buf1);
        iter_kernel<<<grid, blk, 0, stream>>>(srcp, aff, dst);
        srcp = dst;
    }
}

// Round 6
// 345.925 us; speedup vs baseline: 1.0713x; 1.0713x over previous
//
#include <hip/hip_runtime.h>

// Problem constants (from reference)
constexpr int B   = 4;
constexpr int CF  = 3;    // feat channels
constexpr int CM  = 21;   // mask channels
constexpr int H   = 128;
constexpr int W   = 128;
constexpr int KS  = 7;
constexpr int PAD = 3;
constexpr int CENTER = (KS * KS) / 2;  // 24
constexpr int NNB = KS * KS - 1;       // 48 neighbors
constexpr int NUM_ITER = 10;

constexpr int TILE  = 16;
constexpr int TH    = TILE + 2 * PAD;  // 22
constexpr int TS    = 24;              // LDS row stride: ty*24 % 32 in {0,24,16,8} -> exact 2-way aliasing (free)
constexpr int PLANE = TH * TS;         // 528
constexpr int HW    = H * W;
constexpr int NBLK  = (W / TILE) * (H / TILE) * B;  // 256 blocks == 256 CUs -> co-resident

// ---------------------------------------------------------------------------
// Persistent fused kernel: aff in registers, 10 iterations, software grid
// barrier (256 blocks, 1 per CU, guaranteed resident; 768 thr = 12 waves/CU).
// Block: (16,16,3). tz slice owns 7 mask channels; LDS tile shared by slices.
// ---------------------------------------------------------------------------
__global__ __launch_bounds__(768) void fused_kernel(const float* __restrict__ feats,
                                                    const float* __restrict__ mask,
                                                    float* __restrict__ out,
                                                    float* __restrict__ buf0,
                                                    float* __restrict__ buf1,
                                                    unsigned int* __restrict__ ctr) {
    __shared__ float tile[CM][TH][TS];   // 44.4 KB
    float* tf = &tile[0][0][0];

    const int tx = threadIdx.x, ty = threadIdx.y, tz = threadIdx.z;
    const int bx = blockIdx.x * TILE, by = blockIdx.y * TILE;
    const int b  = blockIdx.z;
    const int tid = (tz * TILE + ty) * TILE + tx;
    const int h = by + ty, w = bx + tx;

    // One staging slot per thread (484 halo words per plane, 768 threads)
    const bool sv = tid < TH * TH;
    int gof = 0, lof = 0;
    if (sv) {
        const int r = tid / TH, q = tid - r * TH;
        const int gh = min(max(by + r - PAD, 0), H - 1);
        const int gw = min(max(bx + q - PAD, 0), W - 1);
        gof = gh * W + gw;
        lof = r * TS + q;
    }

    // ---- Phase 1: feats -> LDS, affinity weights into 48 registers ----
    if (sv) {
        const float* fb = feats + (size_t)b * CF * HW;
        #pragma unroll
        for (int c = 0; c < CF; ++c) tf[c * PLANE + lof] = fb[c * HW + gof];
    }
    __syncthreads();

    float qv[CF], inv[CF];
    #pragma unroll
    for (int c = 0; c < CF; ++c) {
        const float* tp = tf + c * PLANE + ty * TS + tx;
        qv[c] = tp[PAD * TS + PAD];
        float s = 0.f, s2 = 0.f;
        #pragma unroll
        for (int i = 0; i < KS; ++i)
            #pragma unroll
            for (int j = 0; j < KS; ++j) {
                if (i == PAD && j == PAD) continue;
                const float v = tp[i * TS + j];
                s += v; s2 += v * v;
            }
        const float mean = s * (1.0f / NNB);
        const float var  = fmaxf(s2 - (float)NNB * mean * mean, 0.f) * (1.0f / (NNB - 1));
        inv[c] = 1.0f / (1e-8f + 0.1f * sqrtf(var));
    }

    float a[NNB];
    {
        float mx = -1e30f;
        #pragma unroll
        for (int i = 0; i < KS; ++i)
            #pragma unroll
            for (int j = 0; j < KS; ++j) {
                const int nn = i * KS + j;
                if (nn == CENTER) continue;
                const int n = (nn < CENTER) ? nn : nn - 1;
                float t = 0.f;
                #pragma unroll
                for (int c = 0; c < CF; ++c)
                    t += fabsf(tf[c * PLANE + (ty + i) * TS + (tx + j)] - qv[c]) * inv[c];
                a[n] = -t * (1.0f / CF);
                mx = fmaxf(mx, a[n]);
            }
        float ssum = 0.f;
        #pragma unroll
        for (int n = 0; n < NNB; ++n) { a[n] = __expf(a[n] - mx); ssum += a[n]; }
        const float rs = 1.0f / ssum;
        #pragma unroll
        for (int n = 0; n < NNB; ++n) a[n] *= rs;
    }
    __syncthreads();   // feats tile no longer needed

    // ---- Phase 2: 10 iterations with software grid barrier ----
    const int c0 = tz * (CM / 3);                 // 7 channels per z-slice
    const float* cur = mask + (size_t)b * CM * HW;

    for (int t = 0; t < NUM_ITER; ++t) {
        float* dstb = ((t == NUM_ITER - 1) ? out : ((t & 1) ? buf1 : buf0))
                      + (size_t)b * CM * HW;

        // stage all 21 channel halo tiles (one slot/thread/channel)
        if (sv) {
            for (int c = 0; c < CM; ++c)
                tf[c * PLANE + lof] = cur[c * HW + gof];
        }
        __syncthreads();

        float* dp = dstb + h * W + w;
        for (int k = 0; k < CM / 3; ++k) {
            const int c = c0 + k;
            const float* tp = tf + c * PLANE + ty * TS + tx;
            float s = 0.f;
            #pragma unroll
            for (int i = 0; i < KS; ++i)
                #pragma unroll
                for (int j = 0; j < KS; ++j) {
                    const int nn = i * KS + j;
                    if (nn == CENTER) continue;
                    const int n = (nn < CENTER) ? nn : nn - 1;
                    s += a[n] * tp[i * TS + j];
                }
            dp[c * HW] = s;
        }
        cur = dstb;

        if (t < NUM_ITER - 1) {
            // grid barrier: all blocks' stores visible before anyone re-stages.
            __syncthreads();                       // drains each wave's vmcnt + converges block
            if (tid == 0) {
                __threadfence();                   // release: write back XCD L2
                __hip_atomic_fetch_add(&ctr[t], 1u, __ATOMIC_RELEASE,
                                       __HIP_MEMORY_SCOPE_AGENT);
                while (__hip_atomic_load(&ctr[t], __ATOMIC_ACQUIRE,
                                         __HIP_MEMORY_SCOPE_AGENT) < (unsigned)NBLK)
                    __builtin_amdgcn_s_sleep(2);
                __threadfence();                   // acquire: invalidate L1/L2
            }
            __syncthreads();
        }
    }
}

// ---------------------------------------------------------------------------
extern "C" void kernel_launch(void* const* d_in, const int* in_sizes, int n_in,
                              void* d_out, int out_size, void* d_ws, size_t ws_size,
                              hipStream_t stream) {
    const float* feats = (const float*)d_in[0];
    const float* mask  = (const float*)d_in[1];
    float* out  = (float*)d_out;

    float* buf0 = (float*)d_ws;                          // 5.5 MB
    float* buf1 = buf0 + (size_t)B * CM * HW;            // 5.5 MB
    unsigned int* ctr = (unsigned int*)(buf1 + (size_t)B * CM * HW);  // 16 words

    // Zero the barrier counters every call (captured into the graph -> every replay)
    hipMemsetAsync(ctr, 0, 16 * sizeof(unsigned int), stream);

    dim3 blk(TILE, TILE, 3);
    dim3 grid(W / TILE, H / TILE, B);
    fused_kernel<<<grid, blk, 0, stream>>>(feats, mask, out, buf0, buf1, ctr);
}

// Round 7
// 184.842 us; speedup vs baseline: 2.0049x; 1.8715x over previous
//
#include <hip/hip_runtime.h>

// Problem constants (from reference)
constexpr int B   = 4;
constexpr int CF  = 3;    // feat channels
constexpr int CM  = 21;   // mask channels
constexpr int H   = 128;
constexpr int W   = 128;
constexpr int KS  = 7;
constexpr int PAD = 3;
constexpr int CENTER = (KS * KS) / 2;  // 24
constexpr int NNB = KS * KS - 1;       // 48 neighbors
constexpr int NUM_ITER = 10;

constexpr int TILE  = 16;
constexpr int TH    = TILE + 2 * PAD;  // 22
constexpr int TS    = 24;              // LDS row stride: ty*24 % 32 in {0,24,16,8} -> exact 2-way aliasing (free)
constexpr int PLANE = TH * TS;         // 528
constexpr int HW    = H * W;
constexpr int TPB   = 768;             // (16,16,3) -> 12 waves/CU

// ---------------------------------------------------------------------------
// Kernel 1: per-pixel 48-way softmax affinity from feats (validated round 4).
// aff layout: aff[((b*48 + n)*H + h)*W + w]  (plane-major, coalesced in w)
// ---------------------------------------------------------------------------
__global__ __launch_bounds__(256) void aff_kernel(const float* __restrict__ feats,
                                                  float* __restrict__ aff) {
    __shared__ float tile[CF][TH][TS];
    const int tx = threadIdx.x, ty = threadIdx.y;
    const int bx = blockIdx.x * TILE, by = blockIdx.y * TILE;
    const int b  = blockIdx.z;
    const int tid = ty * TILE + tx;

    for (int c = 0; c < CF; ++c) {
        const float* src = feats + (size_t)(b * CF + c) * HW;
        for (int idx = tid; idx < TH * TH; idx += 256) {
            const int r  = idx / TH, cc = idx - r * TH;
            const int gh = min(max(by + r  - PAD, 0), H - 1);
            const int gw = min(max(bx + cc - PAD, 0), W - 1);
            tile[c][r][cc] = src[gh * W + gw];
        }
    }
    __syncthreads();

    float q[CF], inv[CF];
    #pragma unroll
    for (int c = 0; c < CF; ++c) {
        const float* tp = &tile[c][ty][tx];
        q[c] = tp[PAD * TS + PAD];
        float s = 0.f, s2 = 0.f;
        #pragma unroll
        for (int i = 0; i < KS; ++i)
            #pragma unroll
            for (int j = 0; j < KS; ++j) {
                if (i == PAD && j == PAD) continue;
                const float v = tp[i * TS + j];
                s += v; s2 += v * v;
            }
        const float mean = s * (1.0f / NNB);
        const float var  = fmaxf(s2 - (float)NNB * mean * mean, 0.f) * (1.0f / (NNB - 1));
        inv[c] = 1.0f / (1e-8f + 0.1f * sqrtf(var));
    }

    float a[NNB];
    float mx = -1e30f;
    #pragma unroll
    for (int i = 0; i < KS; ++i)
        #pragma unroll
        for (int j = 0; j < KS; ++j) {
            const int nn = i * KS + j;
            if (nn == CENTER) continue;
            const int n = (nn < CENTER) ? nn : nn - 1;
            float t = 0.f;
            #pragma unroll
            for (int c = 0; c < CF; ++c)
                t += fabsf(tile[c][ty + i][tx + j] - q[c]) * inv[c];
            a[n] = -t * (1.0f / CF);
            mx = fmaxf(mx, a[n]);
        }
    float ssum = 0.f;
    #pragma unroll
    for (int n = 0; n < NNB; ++n) { a[n] = __expf(a[n] - mx); ssum += a[n]; }
    const float rs = 1.0f / ssum;

    const int h = by + ty, w = bx + tx;
    #pragma unroll
    for (int n = 0; n < NNB; ++n)
        aff[(((size_t)b * NNB + n) * H + h) * W + w] = a[n] * rs;
}

// ---------------------------------------------------------------------------
// Kernel 2: one propagation iteration.
// Block (16,16,3)=768 thr, grid 256 (1/CU, 12 waves). z-slice owns 7 channels.
// aff tile staged to LDS once (49 KB); mask tile 21 planes (44.4 KB);
// ONE __syncthreads per launch. No fences: kernel boundary = visibility.
// ---------------------------------------------------------------------------
__global__ __launch_bounds__(TPB) void iter_kernel(const float* __restrict__ mi,
                                                   const float* __restrict__ aff,
                                                   float* __restrict__ mo) {
    __shared__ float mt[CM][TH][TS];     // 44.4 KB mask halo tiles
    __shared__ float at[NNB][TILE*TILE]; // 49.2 KB aff for the 16x16 pixels
    float* tf = &mt[0][0][0];

    const int tx = threadIdx.x, ty = threadIdx.y, tz = threadIdx.z;
    const int bx = blockIdx.x * TILE, by = blockIdx.y * TILE;
    const int b  = blockIdx.z;
    const int tid  = (tz * TILE + ty) * TILE + tx;
    const int tid2 = ty * TILE + tx;            // slice-local pixel id [0,256)
    const int h = by + ty, w = bx + tx;

    // ---- stage aff planes: 48*256 words, coalesced (consecutive s -> consecutive w)
    {
        const float* ab = aff + (size_t)b * NNB * HW;
        for (int s = tid; s < NNB * TILE * TILE; s += TPB) {
            const int n = s >> 8, p = s & 255;
            const int r = p >> 4, q = p & 15;
            at[n][p] = ab[n * HW + (by + r) * W + (bx + q)];
        }
    }

    // ---- stage mask: each z-slice stages its 7 channels, 2 halo slots/thread
    {
        const float* src = mi + (size_t)(b * CM + tz * (CM / 3)) * HW;
        #pragma unroll
        for (int k = 0; k < 2; ++k) {
            const int slot = tid2 + k * 256;
            if (slot < TH * TH) {
                const int r  = slot / TH, q = slot - r * TH;
                const int gh = min(max(by + r - PAD, 0), H - 1);
                const int gw = min(max(bx + q - PAD, 0), W - 1);
                const int go = gh * W + gw;
                const int lo = r * TS + q;
                #pragma unroll
                for (int c = 0; c < CM / 3; ++c)
                    tf[(tz * (CM / 3) + c) * PLANE + lo] = src[c * HW + go];
            }
        }
    }
    __syncthreads();

    // ---- 48 aff weights -> registers (2-way LDS aliasing = free)
    float a[NNB];
    #pragma unroll
    for (int n = 0; n < NNB; ++n) a[n] = at[n][tid2];

    // ---- 7 channels x 48 taps per thread
    float* dp = mo + (size_t)b * CM * HW + h * W + w;
    #pragma unroll
    for (int k = 0; k < CM / 3; ++k) {
        const int c = tz * (CM / 3) + k;
        const float* tp = tf + c * PLANE + ty * TS + tx;
        float s = 0.f;
        #pragma unroll
        for (int i = 0; i < KS; ++i)
            #pragma unroll
            for (int j = 0; j < KS; ++j) {
                const int nn = i * KS + j;
                if (nn == CENTER) continue;
                const int n = (nn < CENTER) ? nn : nn - 1;
                s += a[n] * tp[i * TS + j];
            }
        dp[c * HW] = s;
    }
}

// ---------------------------------------------------------------------------
extern "C" void kernel_launch(void* const* d_in, const int* in_sizes, int n_in,
                              void* d_out, int out_size, void* d_ws, size_t ws_size,
                              hipStream_t stream) {
    const float* feats = (const float*)d_in[0];
    const float* mask  = (const float*)d_in[1];
    float* out = (float*)d_out;

    float* aff  = (float*)d_ws;                               // 12.58 MB
    float* buf0 = aff  + (size_t)B * NNB * HW;                // 5.5 MB
    float* buf1 = buf0 + (size_t)B * CM  * HW;                // 5.5 MB

    dim3 grid(W / TILE, H / TILE, B);
    aff_kernel<<<grid, dim3(TILE, TILE), 0, stream>>>(feats, aff);

    const float* srcp = mask;
    for (int t = 1; t <= NUM_ITER; ++t) {
        float* dst = (t == NUM_ITER) ? out : ((t & 1) ? buf0 : buf1);
        iter_kernel<<<grid, dim3(TILE, TILE, 3), 0, stream>>>(srcp, aff, dst);
        srcp = dst;
    }
}